// Round 1
// baseline (2921.097 us; speedup 1.0000x reference)
//
#include <hip/hip_runtime.h>

// LeNet C3 sparse conv: x[64,6,512,512] f32 * W_eff[16,6,5,5] -> out[64,16,508,508] + b
// Tile: 4 rows x 64 cols x all 16 oc per block (256 threads).
// Thread: 4 consecutive x positions x 4 output channels = 16 fp32 accumulators.

#define TW 64
#define TH 4
#define IN_W 68   // TW+4
#define IN_H 8    // TH+4

__device__ const int MAPC[6][16] = {
 {1,0,0,0,1,1,1,0,0,1,1,1,1,0,1,1},
 {1,1,0,0,0,1,1,1,0,0,1,1,1,1,0,1},
 {1,1,1,0,0,0,1,1,1,0,0,1,0,1,1,1},
 {0,1,1,1,0,0,1,1,1,1,0,0,1,0,1,1},
 {0,0,1,1,1,0,0,1,1,1,1,0,1,1,0,1},
 {0,0,0,1,1,1,0,0,1,1,1,1,0,1,1,1},
};

__global__ __launch_bounds__(256) void conv_c3(
    const float* __restrict__ x, const float* __restrict__ W,
    const float* __restrict__ b, float* __restrict__ out)
{
    __shared__ float wlds[6*5*5*16];          // [ic*25 + ky*5 + kx][oc]
    __shared__ float ilds[6*IN_H*IN_W];       // [ic][row][col]

    const int tid = threadIdx.x;
    const int tx  = blockIdx.x;     // 0..7   (x tiles, last partial)
    const int ty  = blockIdx.y;     // 0..126 (508 = 4*127)
    const int n   = blockIdx.z;     // 0..63
    const int x0g = tx * TW;
    const int y0  = ty * TH;

    // ---- stage masked weights: layout [ic][ky][kx][oc] for float4-per-4oc reads
    for (int i = tid; i < 2400; i += 256) {
        int oc = i & 15;
        int r  = i >> 4;            // ic*25 + ky*5 + kx
        int ic = r / 25;
        int kk = r % 25;
        float w = W[(oc*6 + ic)*25 + kk];
        wlds[i] = MAPC[ic][oc] ? w : 0.f;
    }

    // ---- stage input tile (rows always in-bounds: y0<=504, cols guarded at 512)
    const float* xn = x + (size_t)n * 6 * 512 * 512;
    for (int i = tid; i < 6*IN_H*IN_W; i += 256) {
        int ic  = i / (IN_H*IN_W);
        int rem = i % (IN_H*IN_W);
        int row = rem / IN_W;
        int col = rem % IN_W;
        int gx  = x0g + col;
        float v = 0.f;
        if (gx < 512) v = xn[((size_t)ic*512 + (y0+row))*512 + gx];
        ilds[i] = v;
    }
    __syncthreads();

    const int xs  = tid & 15;        // x strip: x_local = xs*4
    const int yl  = (tid >> 4) & 3;  // row in tile
    const int ocg = tid >> 6;        // oc group (wave-uniform: 64 lanes share ocg)

    float acc[4][4];                 // [oc_in_group][pos]
    #pragma unroll
    for (int i = 0; i < 4; i++)
        #pragma unroll
        for (int p = 0; p < 4; p++) acc[i][p] = 0.f;

    #pragma unroll
    for (int ic = 0; ic < 6; ic++) {
      #pragma unroll
      for (int ky = 0; ky < 5; ky++) {
        const float* irow = &ilds[(ic*IN_H + yl + ky)*IN_W + xs*4];
        float4 a0 = *(const float4*)irow;        // aligned: 68*4 B row stride, xs*4 floats
        float4 a1 = *(const float4*)(irow + 4);
        float in8[8] = {a0.x,a0.y,a0.z,a0.w,a1.x,a1.y,a1.z,a1.w};
        #pragma unroll
        for (int kx = 0; kx < 5; kx++) {
          // wave-uniform address -> LDS broadcast, conflict-free
          float4 w4 = *(const float4*)&wlds[((ic*5+ky)*5+kx)*16 + ocg*4];
          #pragma unroll
          for (int p = 0; p < 4; p++) {
            float v = in8[kx+p];
            acc[0][p] += v * w4.x;
            acc[1][p] += v * w4.y;
            acc[2][p] += v * w4.z;
            acc[3][p] += v * w4.w;
          }
        }
      }
    }

    // ---- epilogue: bias + float4 store (x tiles are 4-aligned; 508%4==0 ->
    // a strip is either fully in-bounds or fully out)
    const int ox = x0g + xs*4;
    if (ox + 3 < 508) {
      const int oy = y0 + yl;
      #pragma unroll
      for (int i = 0; i < 4; i++) {
        int oc = ocg*4 + i;
        float bias = b[oc];
        float4 r = make_float4(acc[i][0]+bias, acc[i][1]+bias,
                               acc[i][2]+bias, acc[i][3]+bias);
        *(float4*)&out[(((size_t)n*16 + oc)*508 + oy)*508 + ox] = r;
      }
    }
}

extern "C" void kernel_launch(void* const* d_in, const int* in_sizes, int n_in,
                              void* d_out, int out_size, void* d_ws, size_t ws_size,
                              hipStream_t stream) {
    const float* x = (const float*)d_in[0];
    const float* W = (const float*)d_in[1];
    const float* b = (const float*)d_in[2];
    float* out = (float*)d_out;
    dim3 grid(8, 127, 64);   // x tiles, y tiles (508/4), batch
    conv_c3<<<grid, dim3(256), 0, stream>>>(x, W, b, out);
}